// Round 1
// baseline (50.723 us; speedup 1.0000x reference)
//
#include <hip/hip_runtime.h>
#include <hip/hip_bf16.h>

#define B_ROWS 32768
#define D_IN   128
#define H1_    256
#define H2_    256
#define HTAU   32
#define NBLK   128

#define NE     256
#define SMIN  (-8.0f)
#define SMAX  ( 8.0f)

typedef __bf16 bf16_t;
typedef bf16_t bf16x8 __attribute__((ext_vector_type(8)));
typedef float  f32x4  __attribute__((ext_vector_type(4)));

__device__ inline bf16x8 cvt8(const float* v) {
    bf16x8 r;
#pragma unroll
    for (int i = 0; i < 8; ++i) r[i] = (bf16_t)v[i];
    return r;
}

// ---------------------------------------------------------------------------
// Fused mu branch: relu(x@W1^T+b1) -> relu(.@W2^T+b2) -> .@w3^T+b3
// 256 threads (4 waves), 64 rows per workgroup. Each wave: 16 rows x 256 cols.
// W slices staged in LDS in MFMA fragment order (conflict-free linear reads).
// h1 kept in LDS (bf16, XOR-swizzled); h1/h2 never hit global memory.
// ---------------------------------------------------------------------------
__launch_bounds__(256)
__global__ void mu_fused(const float* __restrict__ x,
                         const float* __restrict__ w1, const float* __restrict__ b1,
                         const float* __restrict__ w2, const float* __restrict__ b2,
                         const float* __restrict__ w3, const float* __restrict__ b3,
                         float* __restrict__ mu_out) {
    __shared__ bf16_t wsl[16 * 64 * 8];     // 16KB: [frag][lane][8]
    __shared__ char   h1_raw[64 * 512];     // 32KB: bf16 [64][256], swizzled

    const int tid = threadIdx.x;
    const int l   = tid & 63;
    const int w   = tid >> 6;       // wave 0..3
    const int q   = l >> 4;         // lane quarter 0..3
    const int l15 = l & 15;
    const int rb  = blockIdx.x * 64;

    f32x4 acc[16];
#pragma unroll
    for (int f = 0; f < 16; ++f) acc[f] = (f32x4){0.f, 0.f, 0.f, 0.f};

    // ---------------- layer 1 (K = 128, 4 k-steps) ----------------
    for (int kk = 0; kk < 4; ++kk) {
        // stage W1 k-slice in fragment order: value(c) with nf=c>>6, ll=c&63:
        //   B[k][n] = W1[n][k];  n = nf*16+(ll&15), k = kk*32+(ll>>4)*8 + i
#pragma unroll
        for (int j = 0; j < 4; ++j) {
            int c  = tid + j * 256;
            int nf = c >> 6, ll = c & 63;
            int col = nf * 16 + (ll & 15);
            int kr  = kk * 32 + (ll >> 4) * 8;
            const float* src = w1 + col * D_IN + kr;
            float tmp[8];
            *(f32x4*)tmp       = *(const f32x4*)src;
            *(f32x4*)(tmp + 4) = *(const f32x4*)(src + 4);
            *((bf16x8*)wsl + c) = cvt8(tmp);
        }
        __syncthreads();
        // A-frag straight from global x (f32 -> bf16)
        int row = rb + w * 16 + l15;
        int k0  = kk * 32 + q * 8;
        float av[8];
        *(f32x4*)av       = *(const f32x4*)(x + row * D_IN + k0);
        *(f32x4*)(av + 4) = *(const f32x4*)(x + row * D_IN + k0 + 4);
        bf16x8 a = cvt8(av);
#pragma unroll
        for (int nf = 0; nf < 16; ++nf) {
            bf16x8 b = *((bf16x8*)wsl + nf * 64 + l);
            acc[nf] = __builtin_amdgcn_mfma_f32_16x16x32_bf16(a, b, acc[nf], 0, 0, 0);
        }
        __syncthreads();
    }

    // epilogue 1: h1 = relu(acc + b1) -> LDS bf16, swizzle byte ^= (row&7)<<4
#pragma unroll
    for (int f = 0; f < 16; ++f) {
        int col = f * 16 + l15;
        float bias = b1[col];
#pragma unroll
        for (int r = 0; r < 4; ++r) {
            int rl = q * 4 + r;                 // local row within wave tile
            float v = acc[f][r] + bias;
            v = v > 0.f ? v : 0.f;
            int byte = ((w * 16 + rl) * 512 + col * 2) ^ ((rl & 7) << 4);
            *(bf16_t*)(h1_raw + byte) = (bf16_t)v;
        }
        acc[f] = (f32x4){0.f, 0.f, 0.f, 0.f};
    }
    __syncthreads();

    // ---------------- layer 2 (K = 256, 8 k-steps) ----------------
    for (int kk = 0; kk < 8; ++kk) {
#pragma unroll
        for (int j = 0; j < 4; ++j) {
            int c  = tid + j * 256;
            int nf = c >> 6, ll = c & 63;
            int col = nf * 16 + (ll & 15);
            int kr  = kk * 32 + (ll >> 4) * 8;
            const float* src = w2 + col * H1_ + kr;
            float tmp[8];
            *(f32x4*)tmp       = *(const f32x4*)src;
            *(f32x4*)(tmp + 4) = *(const f32x4*)(src + 4);
            *((bf16x8*)wsl + c) = cvt8(tmp);
        }
        __syncthreads();
        // A-frag from h1 LDS (row = l15 within wave tile)
        int k0   = kk * 32 + q * 8;
        int byte = ((w * 16 + l15) * 512 + k0 * 2) ^ ((l15 & 7) << 4);
        bf16x8 a = *(bf16x8*)(h1_raw + byte);
#pragma unroll
        for (int nf = 0; nf < 16; ++nf) {
            bf16x8 b = *((bf16x8*)wsl + nf * 64 + l);
            acc[nf] = __builtin_amdgcn_mfma_f32_16x16x32_bf16(a, b, acc[nf], 0, 0, 0);
        }
        __syncthreads();
    }

    // epilogue 2: mu = relu(acc + b2) . w3 + b3 (reduce over 256 cols)
    float p[4] = {0.f, 0.f, 0.f, 0.f};
#pragma unroll
    for (int f = 0; f < 16; ++f) {
        int col = f * 16 + l15;
        float bias = b2[col];
        float wv   = w3[col];
#pragma unroll
        for (int r = 0; r < 4; ++r) {
            float v = acc[f][r] + bias;
            v = v > 0.f ? v : 0.f;
            p[r] += v * wv;
        }
    }
#pragma unroll
    for (int m = 1; m < 16; m <<= 1) {
#pragma unroll
        for (int r = 0; r < 4; ++r) p[r] += __shfl_xor(p[r], m, 64);
    }
    if (l15 == 0) {
        float bb = b3[0];
#pragma unroll
        for (int r = 0; r < 4; ++r)
            mu_out[rb + w * 16 + q * 4 + r] = p[r] + bb;
    }
}

// ---------------------------------------------------------------------------
// Tau branch stage 1: tabulate f_n(s) = b_t2[n] + sum_h w_t2[n,h]*softplus(s*w_t1[n,h]+b_t1[n,h])
// 128 blocks x 256 threads; stores duplicated pairs (f[e], f[e+1]) for aligned lerp.
// ---------------------------------------------------------------------------
__global__ void build_tab(const float* __restrict__ wt1, const float* __restrict__ bt1,
                          const float* __restrict__ wt2, const float* __restrict__ bt2,
                          float2* __restrict__ tab2) {
    __shared__ float fv[NE];
    int n = blockIdx.x;
    int e = threadIdx.x;
    float s = SMIN + (SMAX - SMIN) * (float)e / (float)(NE - 1);
    float acc = bt2[n];
    for (int h = 0; h < HTAU; ++h) {
        float z  = s * wt1[n * HTAU + h] + bt1[n * HTAU + h];
        float sp = (z > 20.f) ? z : log1pf(expf(z));
        acc += wt2[n * HTAU + h] * sp;
    }
    fv[e] = acc;
    __syncthreads();
    float nxt = fv[e == NE - 1 ? e : e + 1];
    tab2[n * NE + e] = make_float2(acc, nxt);
}

// ---------------------------------------------------------------------------
// Tau branch stage 2: out_lr[b] = b_lr + sum_n w_lr[n] * lerp(tab[n], x[b,n])
// 256 threads per wg, 64 rows; 4 threads per row (32 n each), LDS reduce.
// ---------------------------------------------------------------------------
__launch_bounds__(256)
__global__ void tau_apply(const float* __restrict__ x, const float2* __restrict__ tab2,
                          const float* __restrict__ wlr, const float* __restrict__ blr,
                          float* __restrict__ out_lr) {
    __shared__ float xs[64 * 129];   // +1 pad: conflict-free column reads
    __shared__ float wl[NBLK];
    __shared__ float part[4][64];

    int tid = threadIdx.x;
    int rb  = blockIdx.x * 64;

    const float4* xg = (const float4*)(x + (size_t)rb * D_IN);
#pragma unroll
    for (int j = 0; j < 8; ++j) {
        int c = tid + j * 256;          // 2048 float4 = 64 rows x 128
        float4 v = xg[c];
        int r = c >> 5;
        int n = (c & 31) * 4;
        xs[r * 129 + n]     = v.x;
        xs[r * 129 + n + 1] = v.y;
        xs[r * 129 + n + 2] = v.z;
        xs[r * 129 + n + 3] = v.w;
    }
    if (tid < NBLK) wl[tid] = wlr[tid];
    __syncthreads();

    int r  = tid & 63;
    int n0 = (tid >> 6) * 32;
    const float INVDS = (float)(NE - 1) / (SMAX - SMIN);
    float acc = 0.f;
#pragma unroll
    for (int j = 0; j < 32; ++j) {
        int n = n0 + j;
        float s = xs[r * 129 + n];
        s = fminf(fmaxf(s, SMIN), SMAX);
        float u = (s - SMIN) * INVDS;
        int i = (int)u;
        i = i > NE - 2 ? NE - 2 : i;
        float fr = u - (float)i;
        float2 tv = tab2[n * NE + i];
        acc += wl[n] * (tv.x + (tv.y - tv.x) * fr);
    }
    part[tid >> 6][r] = acc;
    __syncthreads();
    if (tid < 64) {
        float sum = part[0][tid] + part[1][tid] + part[2][tid] + part[3][tid] + blr[0];
        out_lr[rb + tid] = sum;
    }
}

extern "C" void kernel_launch(void* const* d_in, const int* in_sizes, int n_in,
                              void* d_out, int out_size, void* d_ws, size_t ws_size,
                              hipStream_t stream) {
    const float* x   = (const float*)d_in[0];
    const float* w1  = (const float*)d_in[1];
    const float* b1  = (const float*)d_in[2];
    const float* w2  = (const float*)d_in[3];
    const float* b2  = (const float*)d_in[4];
    const float* w3  = (const float*)d_in[5];
    const float* b3  = (const float*)d_in[6];
    const float* wt1 = (const float*)d_in[7];
    const float* bt1 = (const float*)d_in[8];
    const float* wt2 = (const float*)d_in[9];
    const float* bt2 = (const float*)d_in[10];
    const float* wlr = (const float*)d_in[11];
    const float* blr = (const float*)d_in[12];

    float* out    = (float*)d_out;
    float* mu_out = out;             // output 0: mu  [32768]
    float* lr_out = out + B_ROWS;    // output 1: out_lr [32768]
    float2* tab2  = (float2*)d_ws;   // 128*256*8B = 256KB scratch

    build_tab<<<NBLK, NE, 0, stream>>>(wt1, bt1, wt2, bt2, tab2);
    mu_fused<<<B_ROWS / 64, 256, 0, stream>>>(x, w1, b1, w2, b2, w3, b3, mu_out);
    tau_apply<<<B_ROWS / 64, 256, 0, stream>>>(x, tab2, wlr, blr, lr_out);
}

// Round 2
// 43.116 us; speedup vs baseline: 1.1764x; 1.1764x over previous
//
#include <hip/hip_runtime.h>
#include <hip/hip_bf16.h>

#define B_ROWS 32768
#define D_IN   128
#define H1_    256
#define HTAU   32
#define NBLK   128

#define NE     256
#define SMIN  (-8.0f)
#define SMAX  ( 8.0f)

typedef __bf16 bf16_t;
typedef bf16_t bf16x8 __attribute__((ext_vector_type(8)));
typedef float  f32x4  __attribute__((ext_vector_type(4)));

__device__ __forceinline__ bf16x8 cvt8(const float* v) {
    bf16x8 r;
#pragma unroll
    for (int i = 0; i < 8; ++i) r[i] = (bf16_t)v[i];
    return r;
}

// async global->LDS, 16B per lane; LDS dest = wave-uniform base + lane*16
__device__ __forceinline__ void gload_lds16(const bf16x8* g, bf16x8* l) {
    __builtin_amdgcn_global_load_lds(
        (const __attribute__((address_space(1))) uint32_t*)g,
        (__attribute__((address_space(3))) uint32_t*)l, 16, 0, 0);
}

// ---------------------------------------------------------------------------
// prep: (a) blocks [0,128): tau lookup table  f_n(s) over NE samples
//       (b) blocks [128,176): convert W1,W2 -> bf16 in MFMA fragment order
// fragment order (per k-step kk, chunk c in [0,1024)): nf=c>>6, ll=c&63,
//   col = nf*16 + (ll&15), k = kk*32 + (ll>>4)*8 + i   (i = 0..7)
// ---------------------------------------------------------------------------
__global__ void prep(const float* __restrict__ w1, const float* __restrict__ w2,
                     const float* __restrict__ wt1, const float* __restrict__ bt1,
                     const float* __restrict__ wt2, const float* __restrict__ bt2,
                     float2* __restrict__ tab2,
                     bf16x8* __restrict__ w1f, bf16x8* __restrict__ w2f) {
    __shared__ float fv[NE];
    const int bid = blockIdx.x, tid = threadIdx.x;
    if (bid < NBLK) {
        const int n = bid, e = tid;
        float s = SMIN + (SMAX - SMIN) * (float)e / (float)(NE - 1);
        float acc = bt2[n];
        for (int h = 0; h < HTAU; ++h) {
            float z  = s * wt1[n * HTAU + h] + bt1[n * HTAU + h];
            float sp = (z > 20.f) ? z : log1pf(expf(z));
            acc += wt2[n * HTAU + h] * sp;
        }
        fv[e] = acc;
        __syncthreads();
        float nxt = fv[e == NE - 1 ? e : e + 1];
        tab2[n * NE + e] = make_float2(acc, nxt);
    } else {
        const int cid  = (bid - NBLK) * 256 + tid;      // 0..12287
        const int isW2 = cid >= 4096;
        const int c2   = isW2 ? cid - 4096 : cid;
        const int kk = c2 >> 10, c = c2 & 1023;
        const int nf = c >> 6,  ll = c & 63;
        const int col = nf * 16 + (ll & 15);
        const int kr  = kk * 32 + (ll >> 4) * 8;
        const float* src = isW2 ? (w2 + col * H1_ + kr) : (w1 + col * D_IN + kr);
        float tmp[8];
        *(f32x4*)tmp       = *(const f32x4*)src;
        *(f32x4*)(tmp + 4) = *(const f32x4*)(src + 4);
        (isW2 ? w2f : w1f)[c2] = cvt8(tmp);
    }
}

// ---------------------------------------------------------------------------
// Fused mu branch, BM=128 rows/wg, 8 waves. Weights pre-converted to bf16 in
// fragment order -> staging is pure global_load_lds (16B), zero VALU.
// h1 lives in LDS (bf16, XOR-swizzled). LDS = 16KB stage + 64KB h1 = 80KB.
// ---------------------------------------------------------------------------
__global__ __launch_bounds__(512, 4)
void mu_fused(const float* __restrict__ x,
              const bf16x8* __restrict__ w1f, const bf16x8* __restrict__ w2f,
              const float* __restrict__ b1, const float* __restrict__ b2,
              const float* __restrict__ w3, const float* __restrict__ b3,
              float* __restrict__ mu_out) {
    __shared__ bf16x8 wsl[1024];        // 16KB staged W k-slice, fragment order
    __shared__ char   h1_raw[128 * 512]; // 64KB bf16 [128][256], swizzled

    const int tid = threadIdx.x;
    const int l   = tid & 63;
    const int w   = tid >> 6;           // wave 0..7, owns rows w*16..w*16+15
    const int q   = l >> 4;
    const int l15 = l & 15;
    const int row = w * 16 + l15;       // A-frag row (block-local)
    const int rb  = blockIdx.x * 128;

    f32x4 acc[16];
#pragma unroll
    for (int f = 0; f < 16; ++f) acc[f] = (f32x4){0.f, 0.f, 0.f, 0.f};

    // prefetch all layer-1 A-fragments (x f32 -> bf16), 4 k-steps
    bf16x8 a1[4];
    {
        const float* xr = x + (size_t)(rb + row) * D_IN;
#pragma unroll
        for (int kk = 0; kk < 4; ++kk) {
            float t[8];
            *(f32x4*)t       = *(const f32x4*)(xr + kk * 32 + q * 8);
            *(f32x4*)(t + 4) = *(const f32x4*)(xr + kk * 32 + q * 8 + 4);
            a1[kk] = cvt8(t);
        }
    }

    // ---------------- layer 1 (K = 128, 4 k-steps) ----------------
#pragma unroll
    for (int kk = 0; kk < 4; ++kk) {
        const bf16x8* src = w1f + kk * 1024 + w * 128 + l;
        gload_lds16(src,      &wsl[w * 128]);
        gload_lds16(src + 64, &wsl[w * 128 + 64]);
        __syncthreads();
#pragma unroll
        for (int nf = 0; nf < 16; ++nf)
            acc[nf] = __builtin_amdgcn_mfma_f32_16x16x32_bf16(a1[kk], wsl[nf * 64 + l], acc[nf], 0, 0, 0);
        __syncthreads();
    }

    // epilogue 1: h1 = relu(acc + b1) -> LDS bf16, byte ^= (row&7)<<4
#pragma unroll
    for (int f = 0; f < 16; ++f) {
        int col = f * 16 + l15;
        float bias = b1[col];
#pragma unroll
        for (int r = 0; r < 4; ++r) {
            int gr = w * 16 + q * 4 + r;
            float v = acc[f][r] + bias;
            v = v > 0.f ? v : 0.f;
            int byte = (gr * 512 + col * 2) ^ ((gr & 7) << 4);
            *(bf16_t*)(h1_raw + byte) = (bf16_t)v;
        }
        acc[f] = (f32x4){0.f, 0.f, 0.f, 0.f};
    }
    __syncthreads();

    // ---------------- layer 2 (K = 256, 8 k-steps) ----------------
#pragma unroll
    for (int kk = 0; kk < 8; ++kk) {
        const bf16x8* src = w2f + kk * 1024 + w * 128 + l;
        gload_lds16(src,      &wsl[w * 128]);
        gload_lds16(src + 64, &wsl[w * 128 + 64]);
        int k0   = kk * 32 + q * 8;
        int byte = (row * 512 + k0 * 2) ^ ((row & 7) << 4);
        bf16x8 a = *(bf16x8*)(h1_raw + byte);
        __syncthreads();
#pragma unroll
        for (int nf = 0; nf < 16; ++nf)
            acc[nf] = __builtin_amdgcn_mfma_f32_16x16x32_bf16(a, wsl[nf * 64 + l], acc[nf], 0, 0, 0);
        __syncthreads();
    }

    // epilogue 2: mu = relu(acc + b2) . w3 + b3
    float p[4] = {0.f, 0.f, 0.f, 0.f};
#pragma unroll
    for (int f = 0; f < 16; ++f) {
        int col = f * 16 + l15;
        float bias = b2[col];
        float wv   = w3[col];
#pragma unroll
        for (int r = 0; r < 4; ++r) {
            float v = acc[f][r] + bias;
            v = v > 0.f ? v : 0.f;
            p[r] += v * wv;
        }
    }
#pragma unroll
    for (int m = 1; m < 16; m <<= 1) {
#pragma unroll
        for (int r = 0; r < 4; ++r) p[r] += __shfl_xor(p[r], m, 64);
    }
    if (l15 == 0) {
        float bb = b3[0];
#pragma unroll
        for (int r = 0; r < 4; ++r)
            mu_out[rb + w * 16 + q * 4 + r] = p[r] + bb;
    }
}

// ---------------------------------------------------------------------------
// tau apply: out_lr[b] = b_lr + sum_n w_lr[n] * lerp(tab[n], x[b,n])
// ---------------------------------------------------------------------------
__launch_bounds__(256)
__global__ void tau_apply(const float* __restrict__ x, const float2* __restrict__ tab2,
                          const float* __restrict__ wlr, const float* __restrict__ blr,
                          float* __restrict__ out_lr) {
    __shared__ float xs[64 * 129];
    __shared__ float wl[NBLK];
    __shared__ float part[4][64];

    int tid = threadIdx.x;
    int rb  = blockIdx.x * 64;

    const float4* xg = (const float4*)(x + (size_t)rb * D_IN);
#pragma unroll
    for (int j = 0; j < 8; ++j) {
        int c = tid + j * 256;
        float4 v = xg[c];
        int r = c >> 5;
        int n = (c & 31) * 4;
        xs[r * 129 + n]     = v.x;
        xs[r * 129 + n + 1] = v.y;
        xs[r * 129 + n + 2] = v.z;
        xs[r * 129 + n + 3] = v.w;
    }
    if (tid < NBLK) wl[tid] = wlr[tid];
    __syncthreads();

    int r  = tid & 63;
    int n0 = (tid >> 6) * 32;
    const float INVDS = (float)(NE - 1) / (SMAX - SMIN);
    float acc = 0.f;
#pragma unroll
    for (int j = 0; j < 32; ++j) {
        int n = n0 + j;
        float s = xs[r * 129 + n];
        s = fminf(fmaxf(s, SMIN), SMAX);
        float u = (s - SMIN) * INVDS;
        int i = (int)u;
        i = i > NE - 2 ? NE - 2 : i;
        float fr = u - (float)i;
        float2 tv = tab2[n * NE + i];
        acc += wl[n] * (tv.x + (tv.y - tv.x) * fr);
    }
    part[tid >> 6][r] = acc;
    __syncthreads();
    if (tid < 64) {
        float sum = part[0][tid] + part[1][tid] + part[2][tid] + part[3][tid] + blr[0];
        out_lr[rb + tid] = sum;
    }
}

extern "C" void kernel_launch(void* const* d_in, const int* in_sizes, int n_in,
                              void* d_out, int out_size, void* d_ws, size_t ws_size,
                              hipStream_t stream) {
    const float* x   = (const float*)d_in[0];
    const float* w1  = (const float*)d_in[1];
    const float* b1  = (const float*)d_in[2];
    const float* w2  = (const float*)d_in[3];
    const float* b2  = (const float*)d_in[4];
    const float* w3  = (const float*)d_in[5];
    const float* b3  = (const float*)d_in[6];
    const float* wt1 = (const float*)d_in[7];
    const float* bt1 = (const float*)d_in[8];
    const float* wt2 = (const float*)d_in[9];
    const float* bt2 = (const float*)d_in[10];
    const float* wlr = (const float*)d_in[11];
    const float* blr = (const float*)d_in[12];

    float* out    = (float*)d_out;
    float* mu_out = out;                 // output 0: mu     [32768]
    float* lr_out = out + B_ROWS;        // output 1: out_lr [32768]

    char* ws = (char*)d_ws;
    float2* tab2 = (float2*)ws;                   // 256KB
    bf16x8* w1f  = (bf16x8*)(ws + (256 << 10));   // 64KB  (4096 chunks)
    bf16x8* w2f  = (bf16x8*)(ws + (320 << 10));   // 128KB (8192 chunks)

    prep<<<NBLK + 48, 256, 0, stream>>>(w1, w2, wt1, bt1, wt2, bt2, tab2, w1f, w2f);
    mu_fused<<<B_ROWS / 128, 512, 0, stream>>>(x, w1f, w2f, b1, b2, w3, b3, mu_out);
    tau_apply<<<B_ROWS / 64, 256, 0, stream>>>(x, tab2, wlr, blr, lr_out);
}

// Round 3
// 37.049 us; speedup vs baseline: 1.3691x; 1.1638x over previous
//
#include <hip/hip_runtime.h>
#include <hip/hip_bf16.h>

#define B_ROWS 32768
#define D_IN   128
#define H1_    256
#define HTAU   32
#define NBLK   128

#define NE     64
#define SMIN  (-8.0f)
#define SMAX  ( 8.0f)

typedef __bf16 bf16_t;
typedef bf16_t bf16x8 __attribute__((ext_vector_type(8)));
typedef float  f32x4  __attribute__((ext_vector_type(4)));

__device__ __forceinline__ bf16x8 cvt8(const float* v) {
    bf16x8 r;
#pragma unroll
    for (int i = 0; i < 8; ++i) r[i] = (bf16_t)v[i];
    return r;
}

// async global->LDS, 16B/lane; LDS dest = wave-uniform base + lane*16
__device__ __forceinline__ void gload_lds16(const void* g, void* l) {
    __builtin_amdgcn_global_load_lds(
        (const __attribute__((address_space(1))) uint32_t*)g,
        (__attribute__((address_space(3))) uint32_t*)l, 16, 0, 0);
}

// ---------------------------------------------------------------------------
// prep: blocks [0,32):  tau table  tab[n][e] = f_n(s_e), n = bid*4+(tid>>6),
//                       e = tid&63, NE=64 samples over [-8,8]
//       blocks [32,80): W1,W2 -> bf16 in MFMA fragment order
// fragment order (k-step kk, chunk c in [0,1024)): nf=c>>6, ll=c&63,
//   col = nf*16 + (ll&15), k = kk*32 + (ll>>4)*8 + i   (i = 0..7)
// ---------------------------------------------------------------------------
__global__ void prep(const float* __restrict__ w1, const float* __restrict__ w2,
                     const float* __restrict__ wt1, const float* __restrict__ bt1,
                     const float* __restrict__ wt2, const float* __restrict__ bt2,
                     float* __restrict__ tab,
                     bf16x8* __restrict__ w1f, bf16x8* __restrict__ w2f) {
    const int bid = blockIdx.x, tid = threadIdx.x;
    if (bid < 32) {
        const int n = bid * 4 + (tid >> 6);
        const int e = tid & 63;
        float s = SMIN + (SMAX - SMIN) * (float)e / (float)(NE - 1);
        float acc = bt2[n];
        for (int h = 0; h < HTAU; ++h) {
            float z  = s * wt1[n * HTAU + h] + bt1[n * HTAU + h];
            float sp = (z > 20.f) ? z : log1pf(expf(z));
            acc += wt2[n * HTAU + h] * sp;
        }
        tab[n * NE + e] = acc;
    } else {
        const int cid  = (bid - 32) * 256 + tid;        // 0..12287
        const int isW2 = cid >= 4096;
        const int c2   = isW2 ? cid - 4096 : cid;
        const int kk = c2 >> 10, c = c2 & 1023;
        const int nf = c >> 6,  ll = c & 63;
        const int col = nf * 16 + (ll & 15);
        const int kr  = kk * 32 + (ll >> 4) * 8;
        const float* src = isW2 ? (w2 + col * H1_ + kr) : (w1 + col * D_IN + kr);
        float tmp[8];
        *(f32x4*)tmp       = *(const f32x4*)src;
        *(f32x4*)(tmp + 4) = *(const f32x4*)(src + 4);
        (isW2 ? w2f : w1f)[c2] = cvt8(tmp);
    }
}

// ---------------------------------------------------------------------------
// fused_main: mu branch (MFMA) + tau/out_lr branch, one pass over x.
// 512 threads (8 waves), 128 rows/wg, 256 wgs.
// LDS: 16KB W-stage + 64KB h1 (swizzled bf16) + 32KB tau table + wl = 112.5KB
// Each thread holds x[row][q*8..] for kk=0..3 (32 f32) -> feeds BOTH the
// layer-1 A-fragments (bf16 cvt) and the tau lerp dot (LDS table).
// ---------------------------------------------------------------------------
__global__ __launch_bounds__(512, 2)
void fused_main(const float* __restrict__ x,
                const bf16x8* __restrict__ w1f, const bf16x8* __restrict__ w2f,
                const float* __restrict__ b1, const float* __restrict__ b2,
                const float* __restrict__ w3, const float* __restrict__ b3,
                const float* __restrict__ tabg, const float* __restrict__ wlr,
                const float* __restrict__ blr,
                float* __restrict__ mu_out, float* __restrict__ lr_out) {
    __shared__ bf16x8 wsl[1024];          // 16KB staged W k-slice (frag order)
    __shared__ char   h1_raw[128 * 512];  // 64KB bf16 [128][256], swizzled
    __shared__ float  tab_s[NBLK * NE];   // 32KB tau table
    __shared__ float  wl_s[NBLK];

    const int tid = threadIdx.x;
    const int l   = tid & 63;
    const int w   = tid >> 6;             // wave 0..7
    const int q   = l >> 4;
    const int l15 = l & 15;
    const int row = w * 16 + l15;         // block-local row of this lane
    const int rb  = blockIdx.x * 128;

    // ---- prologue: issue all async staging, load x ----
#pragma unroll
    for (int j = 0; j < 4; ++j) {         // tau table 32KB = 2048 chunks
        int c = tid + j * 512;
        gload_lds16((const char*)tabg + c * 16, (char*)tab_s + c * 16);
    }
    gload_lds16(w1f + w * 128 + l,      &wsl[w * 128]);        // W1 k-step 0
    gload_lds16(w1f + w * 128 + 64 + l, &wsl[w * 128 + 64]);
    if (tid < NBLK) wl_s[tid] = wlr[tid];

    float xv[32];
    {
        const float* xr = x + (size_t)(rb + row) * D_IN;
#pragma unroll
        for (int kk = 0; kk < 4; ++kk) {
            *(f32x4*)(xv + kk * 8)     = *(const f32x4*)(xr + kk * 32 + q * 8);
            *(f32x4*)(xv + kk * 8 + 4) = *(const f32x4*)(xr + kk * 32 + q * 8 + 4);
        }
    }
    bf16x8 a1[4];
#pragma unroll
    for (int kk = 0; kk < 4; ++kk) a1[kk] = cvt8(xv + kk * 8);

    f32x4 acc[16];
#pragma unroll
    for (int f = 0; f < 16; ++f) acc[f] = (f32x4){0.f, 0.f, 0.f, 0.f};

    __syncthreads();   // table + W1k0 + x all resident

    // ---- tau branch: out_lr[row] = blr + sum_n wl[n]*lerp(tab[n], x[row,n])
    {
        const float INVDS = (float)(NE - 1) / (SMAX - SMIN);
        float tsum = 0.f;
#pragma unroll
        for (int kk = 0; kk < 4; ++kk) {
#pragma unroll
            for (int i = 0; i < 8; ++i) {
                float s = xv[kk * 8 + i];
                s = fminf(fmaxf(s, SMIN), SMAX);
                float u = (s - SMIN) * INVDS;
                int ii = (int)u;
                ii = ii > NE - 2 ? NE - 2 : ii;
                float fr = u - (float)ii;
                int nb = (kk * 32 + i) * NE + q * (8 * NE) + ii;
                float t0 = tab_s[nb];
                float t1 = tab_s[nb + 1];
                tsum += wl_s[kk * 32 + q * 8 + i] * (t0 + (t1 - t0) * fr);
            }
        }
        tsum += __shfl_xor(tsum, 16, 64);
        tsum += __shfl_xor(tsum, 32, 64);
        if (q == 0) lr_out[rb + row] = tsum + blr[0];
    }

    // ---- mu layer 1 (K = 128, 4 k-steps) ----
#pragma unroll
    for (int kk = 0; kk < 4; ++kk) {
#pragma unroll
        for (int nf = 0; nf < 16; ++nf)
            acc[nf] = __builtin_amdgcn_mfma_f32_16x16x32_bf16(a1[kk], wsl[nf * 64 + l], acc[nf], 0, 0, 0);

        if (kk == 3) {  // epilogue 1: h1 = relu(acc+b1) -> LDS (wave-local rows)
#pragma unroll
            for (int f = 0; f < 16; ++f) {
                int col = f * 16 + l15;
                float bias = b1[col];
#pragma unroll
                for (int r = 0; r < 4; ++r) {
                    int gr = w * 16 + q * 4 + r;
                    float v = acc[f][r] + bias;
                    v = v > 0.f ? v : 0.f;
                    int byte = (gr * 512 + col * 2) ^ ((gr & 7) << 4);
                    *(bf16_t*)(h1_raw + byte) = (bf16_t)v;
                }
                acc[f] = (f32x4){0.f, 0.f, 0.f, 0.f};
            }
        }
        __syncthreads();                          // all waves done reading wsl
        const bf16x8* src = (kk < 3) ? (w1f + (kk + 1) * 1024) : w2f;
        gload_lds16(src + w * 128 + l,      &wsl[w * 128]);
        gload_lds16(src + w * 128 + 64 + l, &wsl[w * 128 + 64]);
        __syncthreads();                          // next slice resident
    }

    // ---- mu layer 2 (K = 256, 8 k-steps) ----
#pragma unroll
    for (int kk = 0; kk < 8; ++kk) {
        int k0   = kk * 32 + q * 8;
        int byte = (row * 512 + k0 * 2) ^ ((row & 7) << 4);
        bf16x8 a = *(bf16x8*)(h1_raw + byte);
#pragma unroll
        for (int nf = 0; nf < 16; ++nf)
            acc[nf] = __builtin_amdgcn_mfma_f32_16x16x32_bf16(a, wsl[nf * 64 + l], acc[nf], 0, 0, 0);
        if (kk < 7) {
            __syncthreads();
            gload_lds16(w2f + (kk + 1) * 1024 + w * 128 + l,      &wsl[w * 128]);
            gload_lds16(w2f + (kk + 1) * 1024 + w * 128 + 64 + l, &wsl[w * 128 + 64]);
            __syncthreads();
        }
    }

    // ---- epilogue 2: mu = relu(acc + b2) . w3 + b3 ----
    float p[4] = {0.f, 0.f, 0.f, 0.f};
#pragma unroll
    for (int f = 0; f < 16; ++f) {
        int col = f * 16 + l15;
        float bias = b2[col];
        float wv   = w3[col];
#pragma unroll
        for (int r = 0; r < 4; ++r) {
            float v = acc[f][r] + bias;
            v = v > 0.f ? v : 0.f;
            p[r] += v * wv;
        }
    }
#pragma unroll
    for (int m = 1; m < 16; m <<= 1) {
#pragma unroll
        for (int r = 0; r < 4; ++r) p[r] += __shfl_xor(p[r], m, 64);
    }
    if (l15 == 0) {
        float bb = b3[0];
#pragma unroll
        for (int r = 0; r < 4; ++r)
            mu_out[rb + w * 16 + q * 4 + r] = p[r] + bb;
    }
}

extern "C" void kernel_launch(void* const* d_in, const int* in_sizes, int n_in,
                              void* d_out, int out_size, void* d_ws, size_t ws_size,
                              hipStream_t stream) {
    const float* x   = (const float*)d_in[0];
    const float* w1  = (const float*)d_in[1];
    const float* b1  = (const float*)d_in[2];
    const float* w2  = (const float*)d_in[3];
    const float* b2  = (const float*)d_in[4];
    const float* w3  = (const float*)d_in[5];
    const float* b3  = (const float*)d_in[6];
    const float* wt1 = (const float*)d_in[7];
    const float* bt1 = (const float*)d_in[8];
    const float* wt2 = (const float*)d_in[9];
    const float* bt2 = (const float*)d_in[10];
    const float* wlr = (const float*)d_in[11];
    const float* blr = (const float*)d_in[12];

    float* out    = (float*)d_out;
    float* mu_out = out;                 // output 0: mu     [32768]
    float* lr_out = out + B_ROWS;        // output 1: out_lr [32768]

    char* ws = (char*)d_ws;
    float*  tab = (float*)ws;                     // 32KB  (128*64 f32)
    bf16x8* w1f = (bf16x8*)(ws + (32 << 10));     // 64KB  (4096 chunks)
    bf16x8* w2f = (bf16x8*)(ws + (96 << 10));     // 128KB (8192 chunks)

    prep<<<80, 256, 0, stream>>>(w1, w2, wt1, bt1, wt2, bt2, tab, w1f, w2f);
    fused_main<<<B_ROWS / 128, 512, 0, stream>>>(x, w1f, w2f, b1, b2, w3, b3,
                                                 tab, wlr, blr, mu_out, lr_out);
}

// Round 4
// 35.536 us; speedup vs baseline: 1.4274x; 1.0426x over previous
//
#include <hip/hip_runtime.h>
#include <hip/hip_bf16.h>

#define B_ROWS 32768
#define D_IN   128
#define H1_    256
#define HTAU   32
#define NBLK   128

#define NE     64
#define SMIN  (-8.0f)
#define SMAX  ( 8.0f)

typedef __bf16 bf16_t;
typedef bf16_t bf16x8 __attribute__((ext_vector_type(8)));
typedef float  f32x4  __attribute__((ext_vector_type(4)));

__device__ __forceinline__ bf16x8 cvt8(const float* v) {
    bf16x8 r;
#pragma unroll
    for (int i = 0; i < 8; ++i) r[i] = (bf16_t)v[i];
    return r;
}

// async global->LDS, 16B/lane; LDS dest = wave-uniform base + lane*16
__device__ __forceinline__ void gload_lds16(const void* g, void* l) {
    __builtin_amdgcn_global_load_lds(
        (const __attribute__((address_space(1))) uint32_t*)g,
        (__attribute__((address_space(3))) uint32_t*)l, 16, 0, 0);
}

// ---------------------------------------------------------------------------
// prep: blocks [0,32):  tau table pairs tab2[n][e] = (f_n(s_e), f_n(s_{e+1}))
//                       n = bid*4+(tid>>6), e = tid&63, NE=64 over [-8,8]
//       blocks [32,80): W1,W2 -> bf16 in MFMA fragment order
// fragment order (k-step kk, chunk c in [0,1024)): nf=c>>6, ll=c&63,
//   col = nf*16 + (ll&15), k = kk*32 + (ll>>4)*8 + i   (i = 0..7)
// ---------------------------------------------------------------------------
__global__ void prep(const float* __restrict__ w1, const float* __restrict__ w2,
                     const float* __restrict__ wt1, const float* __restrict__ bt1,
                     const float* __restrict__ wt2, const float* __restrict__ bt2,
                     float2* __restrict__ tab2,
                     bf16x8* __restrict__ w1f, bf16x8* __restrict__ w2f) {
    const int bid = blockIdx.x, tid = threadIdx.x;
    if (bid < 32) {
        const int n = bid * 4 + (tid >> 6);
        const int e = tid & 63;
        float s = SMIN + (SMAX - SMIN) * (float)e / (float)(NE - 1);
        float acc = bt2[n];
        for (int h = 0; h < HTAU; ++h) {
            float z  = s * wt1[n * HTAU + h] + bt1[n * HTAU + h];
            float sp = (z > 20.f) ? z : log1pf(expf(z));
            acc += wt2[n * HTAU + h] * sp;
        }
        float nxt = __shfl_down(acc, 1, 64);          // e==63 never interpolated
        tab2[n * NE + e] = make_float2(acc, nxt);
    } else {
        const int cid  = (bid - 32) * 256 + tid;      // 0..12287
        const int isW2 = cid >= 4096;
        const int c2   = isW2 ? cid - 4096 : cid;
        const int kk = c2 >> 10, c = c2 & 1023;
        const int nf = c >> 6,  ll = c & 63;
        const int col = nf * 16 + (ll & 15);
        const int kr  = kk * 32 + (ll >> 4) * 8;
        const float* src = isW2 ? (w2 + col * H1_ + kr) : (w1 + col * D_IN + kr);
        float tmp[8];
        *(f32x4*)tmp       = *(const f32x4*)src;
        *(f32x4*)(tmp + 4) = *(const f32x4*)(src + 4);
        (isW2 ? w2f : w1f)[c2] = cvt8(tmp);
    }
}

// ---------------------------------------------------------------------------
// fused_main: mu branch (MFMA) + tau/out_lr branch, one pass over x.
// BM=64 rows/wg, 256 threads (4 waves), grid 512 -> 2 wgs/CU co-resident:
// one wg's barrier/vmcnt-drain stalls overlap the other's MFMA (m114).
// LDS = 16KB W-stage + 32KB h1 (swizzled bf16) = 48.5KB.
// tau table read as float2 pairs from L2 (64KB, hot across all wgs).
// ---------------------------------------------------------------------------
__global__ __launch_bounds__(256, 2)
void fused_main(const float* __restrict__ x,
                const bf16x8* __restrict__ w1f, const bf16x8* __restrict__ w2f,
                const float* __restrict__ b1, const float* __restrict__ b2,
                const float* __restrict__ w3, const float* __restrict__ b3,
                const float2* __restrict__ tab2, const float* __restrict__ wlr,
                const float* __restrict__ blr,
                float* __restrict__ mu_out, float* __restrict__ lr_out) {
    __shared__ bf16x8 wsl[1024];         // 16KB staged W k-slice (frag order)
    __shared__ char   h1_raw[64 * 512];  // 32KB bf16 [64][256], swizzled

    const int tid = threadIdx.x;
    const int l   = tid & 63;
    const int w   = tid >> 6;            // wave 0..3
    const int q   = l >> 4;
    const int l15 = l & 15;
    const int row = w * 16 + l15;        // block-local row 0..63
    const int rb  = blockIdx.x * 64;

    // ---- prologue: issue W1 k-step 0 staging; load x row; w_lr regs ----
#pragma unroll
    for (int j = 0; j < 4; ++j)
        gload_lds16(w1f + w * 256 + j * 64 + l, &wsl[w * 256 + j * 64]);

    float xv[32], wlv[32];
    {
        const float* xr = x + (size_t)(rb + row) * D_IN;
#pragma unroll
        for (int kk = 0; kk < 4; ++kk) {
            *(f32x4*)(xv + kk * 8)      = *(const f32x4*)(xr + kk * 32 + q * 8);
            *(f32x4*)(xv + kk * 8 + 4)  = *(const f32x4*)(xr + kk * 32 + q * 8 + 4);
            *(f32x4*)(wlv + kk * 8)     = *(const f32x4*)(wlr + kk * 32 + q * 8);
            *(f32x4*)(wlv + kk * 8 + 4) = *(const f32x4*)(wlr + kk * 32 + q * 8 + 4);
        }
    }
    bf16x8 a1[4];
#pragma unroll
    for (int kk = 0; kk < 4; ++kk) a1[kk] = cvt8(xv + kk * 8);

    // ---- tau branch (no LDS dependency; gathers overlap W1 staging) ----
    {
        const float INVDS = (float)(NE - 1) / (SMAX - SMIN);
        float tsum = 0.f;
#pragma unroll
        for (int kk = 0; kk < 4; ++kk) {
#pragma unroll
            for (int i = 0; i < 8; ++i) {
                float s = xv[kk * 8 + i];
                s = fminf(fmaxf(s, SMIN), SMAX);
                float u = (s - SMIN) * INVDS;
                int ii = (int)u;
                ii = ii > NE - 2 ? NE - 2 : ii;
                float fr = u - (float)ii;
                int n = kk * 32 + q * 8 + i;
                float2 tv = tab2[n * NE + ii];
                tsum += wlv[kk * 8 + i] * (tv.x + (tv.y - tv.x) * fr);
            }
        }
        tsum += __shfl_xor(tsum, 16, 64);
        tsum += __shfl_xor(tsum, 32, 64);
        if (q == 0) lr_out[rb + row] = tsum + blr[0];
    }

    f32x4 acc[16];
#pragma unroll
    for (int f = 0; f < 16; ++f) acc[f] = (f32x4){0.f, 0.f, 0.f, 0.f};

    // ---- mu layer 1 (K = 128, 4 k-steps) ----
#pragma unroll
    for (int kk = 0; kk < 4; ++kk) {
        __syncthreads();                  // staged slice resident
#pragma unroll
        for (int nf = 0; nf < 16; ++nf)
            acc[nf] = __builtin_amdgcn_mfma_f32_16x16x32_bf16(a1[kk], wsl[nf * 64 + l], acc[nf], 0, 0, 0);

        if (kk == 3) {  // epilogue 1: h1 = relu(acc+b1) -> LDS, swizzled
#pragma unroll
            for (int f = 0; f < 16; ++f) {
                int col = f * 16 + l15;
                float bias = b1[col];
#pragma unroll
                for (int r = 0; r < 4; ++r) {
                    int gr = w * 16 + q * 4 + r;
                    float v = acc[f][r] + bias;
                    v = v > 0.f ? v : 0.f;
                    int byte = (gr * 512 + col * 2) ^ ((gr & 7) << 4);
                    *(bf16_t*)(h1_raw + byte) = (bf16_t)v;
                }
                acc[f] = (f32x4){0.f, 0.f, 0.f, 0.f};
            }
        }
        __syncthreads();                  // all waves done reading wsl
        const bf16x8* src = (kk < 3) ? (w1f + (kk + 1) * 1024) : w2f;
#pragma unroll
        for (int j = 0; j < 4; ++j)
            gload_lds16(src + w * 256 + j * 64 + l, &wsl[w * 256 + j * 64]);
    }

    // ---- mu layer 2 (K = 256, 8 k-steps) ----
#pragma unroll
    for (int kk = 0; kk < 8; ++kk) {
        __syncthreads();                  // staged slice resident
        int k0   = kk * 32 + q * 8;
        int byte = (row * 512 + k0 * 2) ^ ((row & 7) << 4);
        bf16x8 a = *(bf16x8*)(h1_raw + byte);
#pragma unroll
        for (int nf = 0; nf < 16; ++nf)
            acc[nf] = __builtin_amdgcn_mfma_f32_16x16x32_bf16(a, wsl[nf * 64 + l], acc[nf], 0, 0, 0);
        if (kk < 7) {
            __syncthreads();
#pragma unroll
            for (int j = 0; j < 4; ++j)
                gload_lds16(w2f + (kk + 1) * 1024 + w * 256 + j * 64 + l,
                            &wsl[w * 256 + j * 64]);
        }
    }

    // ---- epilogue 2: mu = relu(acc + b2) . w3 + b3 ----
    float p[4] = {0.f, 0.f, 0.f, 0.f};
#pragma unroll
    for (int f = 0; f < 16; ++f) {
        int col = f * 16 + l15;
        float bias = b2[col];
        float wv   = w3[col];
#pragma unroll
        for (int r = 0; r < 4; ++r) {
            float v = acc[f][r] + bias;
            v = v > 0.f ? v : 0.f;
            p[r] += v * wv;
        }
    }
#pragma unroll
    for (int m = 1; m < 16; m <<= 1) {
#pragma unroll
        for (int r = 0; r < 4; ++r) p[r] += __shfl_xor(p[r], m, 64);
    }
    if (l15 == 0) {
        float bb = b3[0];
#pragma unroll
        for (int r = 0; r < 4; ++r)
            mu_out[rb + w * 16 + q * 4 + r] = p[r] + bb;
    }
}

extern "C" void kernel_launch(void* const* d_in, const int* in_sizes, int n_in,
                              void* d_out, int out_size, void* d_ws, size_t ws_size,
                              hipStream_t stream) {
    const float* x   = (const float*)d_in[0];
    const float* w1  = (const float*)d_in[1];
    const float* b1  = (const float*)d_in[2];
    const float* w2  = (const float*)d_in[3];
    const float* b2  = (const float*)d_in[4];
    const float* w3  = (const float*)d_in[5];
    const float* b3  = (const float*)d_in[6];
    const float* wt1 = (const float*)d_in[7];
    const float* bt1 = (const float*)d_in[8];
    const float* wt2 = (const float*)d_in[9];
    const float* bt2 = (const float*)d_in[10];
    const float* wlr = (const float*)d_in[11];
    const float* blr = (const float*)d_in[12];

    float* out    = (float*)d_out;
    float* mu_out = out;                 // output 0: mu     [32768]
    float* lr_out = out + B_ROWS;        // output 1: out_lr [32768]

    char* ws = (char*)d_ws;
    float2* tab2 = (float2*)ws;                   // 64KB  (128*64 float2)
    bf16x8* w1f  = (bf16x8*)(ws + (64 << 10));    // 64KB  (4096 chunks)
    bf16x8* w2f  = (bf16x8*)(ws + (128 << 10));   // 128KB (8192 chunks)

    prep<<<80, 256, 0, stream>>>(w1, w2, wt1, bt1, wt2, bt2, tab2, w1f, w2f);
    fused_main<<<B_ROWS / 64, 256, 0, stream>>>(x, w1f, w2f, b1, b2, w3, b3,
                                                tab2, wlr, blr, mu_out, lr_out);
}